// Round 1
// baseline (1117.134 us; speedup 1.0000x reference)
//
#include <hip/hip_runtime.h>
#include <stdint.h>

typedef unsigned short u16;
typedef __attribute__((ext_vector_type(8))) short short8;
typedef __attribute__((ext_vector_type(4))) float floatx4;

#define BN_EPS 1e-5f

__device__ __forceinline__ float bf2f(u16 u) { return __uint_as_float(((unsigned)u) << 16); }
__device__ __forceinline__ u16 f2bf(float f) {
  unsigned u = __float_as_uint(f);
  u += 0x7FFFu + ((u >> 16) & 1u);   // round-to-nearest-even
  return (u16)(u >> 16);
}

// ---------------------------------------------------------------------------
// init: fill out (f32) with -inf, zero stats block
__global__ void k_init(float* __restrict__ outf, long n_outf, float* __restrict__ stats) {
  long i = (long)blockIdx.x * blockDim.x + threadIdx.x;
  long stride = (long)gridDim.x * blockDim.x;
  for (long j = i; j < n_outf; j += stride) outf[j] = __uint_as_float(0xFF800000u);
  if (i < 512) stats[i] = 0.f;
}

// ---------------------------------------------------------------------------
// global Frobenius norm of all edge directions: sum of squares -> stats[0]
__global__ void k_norm(const int* __restrict__ ei, const float* __restrict__ pos, int E,
                       float* __restrict__ stats) {
  int tid = blockIdx.x * blockDim.x + threadIdx.x;
  int stride = gridDim.x * blockDim.x;
  float acc = 0.f;
  for (int e = tid; e < E; e += stride) {
    int s = ei[e], d = ei[E + e];
    float d0 = pos[3 * s + 0] - pos[3 * d + 0];
    float d1 = pos[3 * s + 1] - pos[3 * d + 1];
    float d2 = pos[3 * s + 2] - pos[3 * d + 2];
    acc = fmaf(d0, d0, acc);
    acc = fmaf(d1, d1, acc);
    acc = fmaf(d2, d2, acc);
  }
#pragma unroll
  for (int off = 32; off > 0; off >>= 1) acc += __shfl_down(acc, off, 64);
  if ((threadIdx.x & 63) == 0) atomicAdd(&stats[0], acc);
}

// ---------------------------------------------------------------------------
// layer 1: h = relu([dir, x_dst] @ W1 + b1), f32 compute, bf16 store, fused stats
// wave-per-edge, lane = output channel
__global__ void k_layer1(const int* __restrict__ ei, const float* __restrict__ pos,
                         const float* __restrict__ x, const float* __restrict__ W1,
                         const float* __restrict__ b1, u16* __restrict__ h,
                         const float* __restrict__ stats, float* __restrict__ gsum,
                         float* __restrict__ gsq, int E) {
  float invn = 1.0f / sqrtf(stats[0]);
  int lane = threadIdx.x & 63;
  int gw = ((int)blockIdx.x * (blockDim.x >> 6)) + (threadIdx.x >> 6);
  int nw = (int)gridDim.x * (blockDim.x >> 6);
  float w[6];
#pragma unroll
  for (int k = 0; k < 6; k++) w[k] = W1[k * 64 + lane];
  float bias = b1[lane];
  float psum = 0.f, psq = 0.f;
  for (int e = gw; e < E; e += nw) {
    int s = ei[e], d = ei[E + e];
    float in[6];
#pragma unroll
    for (int k = 0; k < 3; k++) in[k] = (pos[3 * s + k] - pos[3 * d + k]) * invn;
#pragma unroll
    for (int k = 0; k < 3; k++) in[3 + k] = x[3 * d + k];
    float acc = bias;
#pragma unroll
    for (int k = 0; k < 6; k++) acc = fmaf(in[k], w[k], acc);
    acc = fmaxf(acc, 0.f);
    u16 hb = f2bf(acc);
    h[(long)e * 64 + lane] = hb;
    float hf = bf2f(hb);
    psum += hf;
    psq = fmaf(hf, hf, psq);
  }
  __shared__ float ssum[64], ssq[64];
  if (threadIdx.x < 64) { ssum[threadIdx.x] = 0.f; ssq[threadIdx.x] = 0.f; }
  __syncthreads();
  atomicAdd(&ssum[lane], psum);
  atomicAdd(&ssq[lane], psq);
  __syncthreads();
  if (threadIdx.x < 64) {
    atomicAdd(&gsum[threadIdx.x], ssum[threadIdx.x]);
    atomicAdd(&gsq[threadIdx.x], ssq[threadIdx.x]);
  }
}

// ---------------------------------------------------------------------------
// BN finalize: scale = g*rsqrt(var+eps), shift = be - mu*scale   (1 block, 64 thr)
__global__ void k_fin(const float* __restrict__ gsum, const float* __restrict__ gsq,
                      const float* __restrict__ g, const float* __restrict__ be,
                      float* __restrict__ scale, float* __restrict__ shift, float invE) {
  int c = threadIdx.x;
  float mu = gsum[c] * invE;
  float var = gsq[c] * invE - mu * mu;
  float s = g[c] * rsqrtf(var + BN_EPS);
  scale[c] = s;
  shift[c] = be[c] - mu * s;
}

// ---------------------------------------------------------------------------
// layers 2/3: h = relu( bn_in(h) @ W + b ), in place, bf16 MFMA, fused stats
// wave handles 16 edges x 64 channels; K=64 via 2 MFMA k-steps; W in 32 VGPRs.
__global__ void k_layer_mfma(u16* h, const float* __restrict__ W, const float* __restrict__ b,
                             const float* __restrict__ scale_in, const float* __restrict__ shift_in,
                             float* __restrict__ gsum, float* __restrict__ gsq, int E) {
  int lane = threadIdx.x & 63;
  int m = lane & 15;   // A row / D col index
  int q = lane >> 4;   // quad

  // B fragments: B[k][n], n = lane&15, k = q*8+j (+32 per k-step). t = n-tile of 16.
  short8 bf[4][2];
#pragma unroll
  for (int t = 0; t < 4; t++)
#pragma unroll
    for (int s = 0; s < 2; s++)
#pragma unroll
      for (int j = 0; j < 8; j++)
        bf[t][s][j] = (short)f2bf(W[(s * 32 + q * 8 + j) * 64 + t * 16 + m]);

  float bias[4];
#pragma unroll
  for (int t = 0; t < 4; t++) bias[t] = b[t * 16 + m];

  float sc[2][8], sh[2][8];
#pragma unroll
  for (int s = 0; s < 2; s++)
#pragma unroll
    for (int j = 0; j < 8; j++) {
      sc[s][j] = scale_in[s * 32 + q * 8 + j];
      sh[s][j] = shift_in[s * 32 + q * 8 + j];
    }

  float psum[4] = {0.f, 0.f, 0.f, 0.f}, psq[4] = {0.f, 0.f, 0.f, 0.f};

  int tiles = E >> 4;
  int gw = ((int)blockIdx.x * (blockDim.x >> 6)) + (threadIdx.x >> 6);
  int nw = (int)gridDim.x * (blockDim.x >> 6);

  for (int tile = gw; tile < tiles; tile += nw) {
    long e0 = (long)tile * 16;
    const u16* rowp = h + (e0 + m) * 64;
    short8 a[2];
#pragma unroll
    for (int s = 0; s < 2; s++) {
      uint4 raw = *(const uint4*)(rowp + s * 32 + q * 8);
      unsigned rw[4] = {raw.x, raw.y, raw.z, raw.w};
#pragma unroll
      for (int p = 0; p < 4; p++) {
        float v0 = bf2f((u16)(rw[p] & 0xFFFFu));
        float v1 = bf2f((u16)(rw[p] >> 16));
        v0 = fmaf(v0, sc[s][2 * p], sh[s][2 * p]);
        v1 = fmaf(v1, sc[s][2 * p + 1], sh[s][2 * p + 1]);
        a[s][2 * p] = (short)f2bf(v0);
        a[s][2 * p + 1] = (short)f2bf(v1);
      }
    }
    floatx4 acc[4];
#pragma unroll
    for (int t = 0; t < 4; t++) acc[t] = (floatx4){0.f, 0.f, 0.f, 0.f};
#pragma unroll
    for (int t = 0; t < 4; t++)
      acc[t] = __builtin_amdgcn_mfma_f32_16x16x32_bf16(a[0], bf[t][0], acc[t], 0, 0, 0);
#pragma unroll
    for (int t = 0; t < 4; t++)
      acc[t] = __builtin_amdgcn_mfma_f32_16x16x32_bf16(a[1], bf[t][1], acc[t], 0, 0, 0);

#pragma unroll
    for (int t = 0; t < 4; t++) {
#pragma unroll
      for (int r = 0; r < 4; r++) {
        float v = acc[t][r] + bias[t];
        v = fmaxf(v, 0.f);
        u16 hb = f2bf(v);
        h[(e0 + q * 4 + r) * 64 + t * 16 + m] = hb;
        float hf = bf2f(hb);
        psum[t] += hf;
        psq[t] = fmaf(hf, hf, psq[t]);
      }
    }
  }

  // channel c = t*16+m partials live in 4 quads -> reduce, then block, then global
#pragma unroll
  for (int t = 0; t < 4; t++) {
    psum[t] += __shfl_xor(psum[t], 16, 64);
    psum[t] += __shfl_xor(psum[t], 32, 64);
    psq[t] += __shfl_xor(psq[t], 16, 64);
    psq[t] += __shfl_xor(psq[t], 32, 64);
  }
  __shared__ float ssum[64], ssq[64];
  if (threadIdx.x < 64) { ssum[threadIdx.x] = 0.f; ssq[threadIdx.x] = 0.f; }
  __syncthreads();
  if (q == 0) {
#pragma unroll
    for (int t = 0; t < 4; t++) {
      atomicAdd(&ssum[t * 16 + m], psum[t]);
      atomicAdd(&ssq[t * 16 + m], psq[t]);
    }
  }
  __syncthreads();
  if (threadIdx.x < 64) {
    atomicAdd(&gsum[threadIdx.x], ssum[threadIdx.x]);
    atomicAdd(&gsq[threadIdx.x], ssq[threadIdx.x]);
  }
}

// ---------------------------------------------------------------------------
// scatter max: out[dst][c] = max(out[dst][c], bn3(h3)); f32 atomic max trick
__global__ void k_scatter(const int* __restrict__ ei, const u16* __restrict__ h,
                          const float* __restrict__ scale, const float* __restrict__ shift,
                          float* outf, int E) {
  int lane = threadIdx.x & 63;
  int gw = ((int)blockIdx.x * (blockDim.x >> 6)) + (threadIdx.x >> 6);
  int nw = (int)gridDim.x * (blockDim.x >> 6);
  float sc = scale[lane], sh = shift[lane];
  for (int e = gw; e < E; e += nw) {
    int d = ei[E + e];
    float v = fmaf(bf2f(h[(long)e * 64 + lane]), sc, sh);
    float* addr = outf + (long)d * 64 + lane;
    if (v >= 0.f)
      atomicMax((int*)addr, __float_as_int(v));
    else
      atomicMin((unsigned int*)addr, __float_as_uint(v));
  }
}

// ---------------------------------------------------------------------------
// fixup: empty segments (-inf) -> 0, in place on d_out
__global__ void k_out(float* __restrict__ outf, long n) {
  long i = (long)blockIdx.x * blockDim.x + threadIdx.x;
  long stride = (long)gridDim.x * blockDim.x;
  for (long j = i; j < n; j += stride) {
    float v = outf[j];
    unsigned u = __float_as_uint(v);
    if ((u & 0x7F800000u) == 0x7F800000u) v = 0.f;  // non-finite -> 0
    outf[j] = v;
  }
}

// ---------------------------------------------------------------------------
extern "C" void kernel_launch(void* const* d_in, const int* in_sizes, int n_in,
                              void* d_out, int out_size, void* d_ws, size_t ws_size,
                              hipStream_t stream) {
  const float* x = (const float*)d_in[0];
  const float* pos = (const float*)d_in[1];
  const int* ei = (const int*)d_in[2];
  const float* W1 = (const float*)d_in[3];
  const float* b1 = (const float*)d_in[4];
  const float* g1 = (const float*)d_in[5];
  const float* be1 = (const float*)d_in[6];
  const float* W2 = (const float*)d_in[7];
  const float* b2 = (const float*)d_in[8];
  const float* g2 = (const float*)d_in[9];
  const float* be2 = (const float*)d_in[10];
  const float* W3 = (const float*)d_in[11];
  const float* b3 = (const float*)d_in[12];
  const float* g3 = (const float*)d_in[13];
  const float* be3 = (const float*)d_in[14];

  int N = in_sizes[0] / 3;
  int E = in_sizes[2] / 2;
  long n_out = (long)N * 64;

  char* wsb = (char*)d_ws;
  u16* h = (u16*)wsb;                                   // [E,64] bf16 activations
  size_t hbytes = (size_t)E * 64 * 2;
  float* stats = (float*)(wsb + hbytes);                // 512-float stats block + params

  float* gsum1 = stats + 64, * gsq1 = stats + 128;
  float* gsum2 = stats + 192, * gsq2 = stats + 256;
  float* gsum3 = stats + 320, * gsq3 = stats + 384;
  float* sc1 = stats + 512, * sh1 = stats + 576;
  float* sc2 = stats + 640, * sh2 = stats + 704;
  float* sc3 = stats + 768, * sh3 = stats + 832;

  float* outf = (float*)d_out;
  float invE = 1.0f / (float)E;

  k_init<<<4096, 256, 0, stream>>>(outf, n_out, stats);
  k_norm<<<2048, 256, 0, stream>>>(ei, pos, E, stats);
  k_layer1<<<2048, 256, 0, stream>>>(ei, pos, x, W1, b1, h, stats, gsum1, gsq1, E);
  k_fin<<<1, 64, 0, stream>>>(gsum1, gsq1, g1, be1, sc1, sh1, invE);
  k_layer_mfma<<<1024, 256, 0, stream>>>(h, W2, b2, sc1, sh1, gsum2, gsq2, E);
  k_fin<<<1, 64, 0, stream>>>(gsum2, gsq2, g2, be2, sc2, sh2, invE);
  k_layer_mfma<<<1024, 256, 0, stream>>>(h, W3, b3, sc2, sh2, gsum3, gsq3, E);
  k_fin<<<1, 64, 0, stream>>>(gsum3, gsq3, g3, be3, sc3, sh3, invE);
  k_scatter<<<2048, 256, 0, stream>>>(ei, h, sc3, sh3, outf, E);
  k_out<<<2048, 256, 0, stream>>>(outf, n_out);
}

// Round 2
// 628.133 us; speedup vs baseline: 1.7785x; 1.7785x over previous
//
#include <hip/hip_runtime.h>
#include <stdint.h>

typedef unsigned short u16;
typedef unsigned int u32;
typedef __attribute__((ext_vector_type(8))) short short8;
typedef __attribute__((ext_vector_type(4))) float floatx4;

#define BN_EPS 1e-5f
#define NPB 256    // nodes per bucket (power of 2; bucket = dst >> 8)
#define NBMAX 512

__device__ __forceinline__ float bf2f(u16 u) { return __uint_as_float(((unsigned)u) << 16); }
__device__ __forceinline__ u16 f2bf(float f) {
  unsigned u = __float_as_uint(f);
  u += 0x7FFFu + ((u >> 16) & 1u);   // round-to-nearest-even
  return (u16)(u >> 16);
}
// order-preserving float<->u32 key (key 0 == "empty"; real values always > 0)
__device__ __forceinline__ u32 fkey(float f) {
  unsigned u = __float_as_uint(f);
  return (u >> 31) ? ~u : (u | 0x80000000u);
}
__device__ __forceinline__ float funkey(u32 k) {
  return (k & 0x80000000u) ? __uint_as_float(k ^ 0x80000000u) : __uint_as_float(~k);
}

// ---------------------------------------------------------------------------
// zero the small control block (stats + bucket totals)
__global__ void k_init(float* __restrict__ stats, u32* __restrict__ bucketTotal) {
  for (int i = threadIdx.x; i < 1024; i += blockDim.x) stats[i] = 0.f;
  for (int i = threadIdx.x; i < NBMAX + 1; i += blockDim.x) bucketTotal[i] = 0u;
}

// ---------------------------------------------------------------------------
// fused: global sum-of-squares of directions + per-bucket dst histogram
__global__ void k_norm_hist(const int* __restrict__ ei, const float* __restrict__ pos,
                            int E, int NB, float* __restrict__ stats,
                            u32* __restrict__ bucketTotal) {
  __shared__ u32 lh[NBMAX];
  __shared__ float red[16];
  for (int i = threadIdx.x; i < NB; i += blockDim.x) lh[i] = 0u;
  __syncthreads();
  int tid = blockIdx.x * blockDim.x + threadIdx.x;
  int stride = gridDim.x * blockDim.x;
  float acc = 0.f;
  for (int e = tid; e < E; e += stride) {
    int s = ei[e], d = ei[E + e];
    float d0 = pos[3 * s + 0] - pos[3 * d + 0];
    float d1 = pos[3 * s + 1] - pos[3 * d + 1];
    float d2 = pos[3 * s + 2] - pos[3 * d + 2];
    acc = fmaf(d0, d0, acc);
    acc = fmaf(d1, d1, acc);
    acc = fmaf(d2, d2, acc);
    atomicAdd(&lh[d >> 8], 1u);
  }
#pragma unroll
  for (int off = 32; off > 0; off >>= 1) acc += __shfl_down(acc, off, 64);
  if ((threadIdx.x & 63) == 0) red[threadIdx.x >> 6] = acc;
  __syncthreads();
  if (threadIdx.x == 0) {
    float s = 0.f;
    for (int w = 0; w < (int)(blockDim.x >> 6); w++) s += red[w];
    atomicAdd(&stats[0], s);
  }
  for (int i = threadIdx.x; i < NB; i += blockDim.x)
    if (lh[i]) atomicAdd(&bucketTotal[i], lh[i]);
}

// ---------------------------------------------------------------------------
// exclusive scan of bucket totals (tiny; single thread)
__global__ void k_scan(const u32* __restrict__ bucketTotal, u32* __restrict__ base,
                       u32* __restrict__ cursor, int NB) {
  if (threadIdx.x == 0 && blockIdx.x == 0) {
    u32 run = 0;
    for (int b = 0; b < NB; b++) {
      base[b] = run;
      cursor[b] = run;
      run += bucketTotal[b];
    }
    base[NB] = run;
  }
}

// ---------------------------------------------------------------------------
// bin edge ids by dst bucket: sorted[slot] = (e << 8) | (dst & 255)
__global__ void k_place(const int* __restrict__ ei, int E, int NB,
                        u32* __restrict__ cursor, u32* __restrict__ sorted) {
  __shared__ u32 lh[NBMAX];
  __shared__ u32 lbase[NBMAX];
  for (int i = threadIdx.x; i < NB; i += blockDim.x) lh[i] = 0u;
  __syncthreads();
  int tid = blockIdx.x * blockDim.x + threadIdx.x;
  int stride = gridDim.x * blockDim.x;
  for (int e = tid; e < E; e += stride) atomicAdd(&lh[ei[E + e] >> 8], 1u);
  __syncthreads();
  for (int i = threadIdx.x; i < NB; i += blockDim.x) {
    u32 c = lh[i];
    lbase[i] = c ? atomicAdd(&cursor[i], c) : 0u;
    lh[i] = 0u;
  }
  __syncthreads();
  for (int e = tid; e < E; e += stride) {
    int d = ei[E + e];
    int b = d >> 8;
    u32 slot = lbase[b] + atomicAdd(&lh[b], 1u);
    sorted[slot] = ((u32)e << 8) | (u32)(d & 255);
  }
}

// ---------------------------------------------------------------------------
// per-bucket scatter-max in LDS: gather h3 rows, apply BN3, atomicMax keys,
// then one coalesced write of the 256-node tile. Empty nodes -> 0.
__global__ __launch_bounds__(512) void k_bucket_max(
    const u32* __restrict__ sorted, const u32* __restrict__ base,
    const u16* __restrict__ h, const float* __restrict__ sc3,
    const float* __restrict__ sh3, float* __restrict__ outf, int N) {
  __shared__ u32 tile[NPB * 64];  // 64 KB of order-preserving keys
  for (int i = threadIdx.x; i < NPB * 64; i += blockDim.x) tile[i] = 0u;
  int b = blockIdx.x;
  u32 start = base[b];
  int cnt = (int)(base[b + 1] - start);
  int t = threadIdx.x;
  int es = t >> 3;       // edge slot 0..63
  int c0 = (t & 7) * 8;  // this thread's 8 channels
  float sc[8], sh[8];
#pragma unroll
  for (int j = 0; j < 8; j++) { sc[j] = sc3[c0 + j]; sh[j] = sh3[c0 + j]; }
  __syncthreads();

  for (int i0 = 0; i0 < cnt; i0 += 256) {  // 64 edges x 4-deep unroll
    u32 pk[4];
    uint4 raw[4];
    int ok[4];
#pragma unroll
    for (int u_ = 0; u_ < 4; u_++) {
      int sl = i0 + u_ * 64 + es;
      ok[u_] = sl < cnt;
      pk[u_] = ok[u_] ? sorted[start + sl] : 0u;
    }
#pragma unroll
    for (int u_ = 0; u_ < 4; u_++)
      if (ok[u_]) raw[u_] = *(const uint4*)(h + (long)(pk[u_] >> 8) * 64 + c0);
#pragma unroll
    for (int u_ = 0; u_ < 4; u_++) {
      if (!ok[u_]) continue;
      int ln = (int)(pk[u_] & 255u);
      unsigned w[4] = {raw[u_].x, raw[u_].y, raw[u_].z, raw[u_].w};
      u32 key[8];
#pragma unroll
      for (int p = 0; p < 4; p++) {
        float v0 = bf2f((u16)(w[p] & 0xFFFFu));
        float v1 = bf2f((u16)(w[p] >> 16));
        key[2 * p] = fkey(fmaf(v0, sc[2 * p], sh[2 * p]));
        key[2 * p + 1] = fkey(fmaf(v1, sc[2 * p + 1], sh[2 * p + 1]));
      }
      // per-edge-slot rotated channel order -> 2 lanes/bank (conflict-free)
#pragma unroll
      for (int jj = 0; jj < 8; jj++) {
        int j = (jj + es) & 7;
        atomicMax(&tile[ln * 64 + c0 + j], key[j]);
      }
    }
  }
  __syncthreads();
  int node0 = b * NPB;
  for (int l = t; l < NPB * 64; l += blockDim.x) {
    int node = node0 + (l >> 6);
    if (node < N) {
      u32 k = tile[l];
      outf[(long)node * 64 + (l & 63)] = (k == 0u) ? 0.f : funkey(k);
    }
  }
}

// ---------------------------------------------------------------------------
// layer 1: h = relu([dir, x_dst] @ W1 + b1), f32 compute, bf16 store, fused stats
__global__ void k_layer1(const int* __restrict__ ei, const float* __restrict__ pos,
                         const float* __restrict__ x, const float* __restrict__ W1,
                         const float* __restrict__ b1, u16* __restrict__ h,
                         const float* __restrict__ stats, float* __restrict__ gsum,
                         float* __restrict__ gsq, int E) {
  float invn = 1.0f / sqrtf(stats[0]);
  int lane = threadIdx.x & 63;
  int gw = ((int)blockIdx.x * (blockDim.x >> 6)) + (threadIdx.x >> 6);
  int nw = (int)gridDim.x * (blockDim.x >> 6);
  float w[6];
#pragma unroll
  for (int k = 0; k < 6; k++) w[k] = W1[k * 64 + lane];
  float bias = b1[lane];
  float psum = 0.f, psq = 0.f;
  for (int e = gw; e < E; e += nw) {
    int s = ei[e], d = ei[E + e];
    float in[6];
#pragma unroll
    for (int k = 0; k < 3; k++) in[k] = (pos[3 * s + k] - pos[3 * d + k]) * invn;
#pragma unroll
    for (int k = 0; k < 3; k++) in[3 + k] = x[3 * d + k];
    float acc = bias;
#pragma unroll
    for (int k = 0; k < 6; k++) acc = fmaf(in[k], w[k], acc);
    acc = fmaxf(acc, 0.f);
    u16 hb = f2bf(acc);
    h[(long)e * 64 + lane] = hb;
    float hf = bf2f(hb);
    psum += hf;
    psq = fmaf(hf, hf, psq);
  }
  __shared__ float ssum[64], ssq[64];
  if (threadIdx.x < 64) { ssum[threadIdx.x] = 0.f; ssq[threadIdx.x] = 0.f; }
  __syncthreads();
  atomicAdd(&ssum[lane], psum);
  atomicAdd(&ssq[lane], psq);
  __syncthreads();
  if (threadIdx.x < 64) {
    atomicAdd(&gsum[threadIdx.x], ssum[threadIdx.x]);
    atomicAdd(&gsq[threadIdx.x], ssq[threadIdx.x]);
  }
}

// ---------------------------------------------------------------------------
// BN finalize (1 block, 64 thr)
__global__ void k_fin(const float* __restrict__ gsum, const float* __restrict__ gsq,
                      const float* __restrict__ g, const float* __restrict__ be,
                      float* __restrict__ scale, float* __restrict__ shift, float invE) {
  int c = threadIdx.x;
  float mu = gsum[c] * invE;
  float var = gsq[c] * invE - mu * mu;
  float s = g[c] * rsqrtf(var + BN_EPS);
  scale[c] = s;
  shift[c] = be[c] - mu * s;
}

// ---------------------------------------------------------------------------
// layers 2/3: h = relu( bn_in(h) @ W + b ), in place, bf16 MFMA, fused stats
__global__ void k_layer_mfma(u16* h, const float* __restrict__ W, const float* __restrict__ b,
                             const float* __restrict__ scale_in, const float* __restrict__ shift_in,
                             float* __restrict__ gsum, float* __restrict__ gsq, int E) {
  int lane = threadIdx.x & 63;
  int m = lane & 15;
  int q = lane >> 4;

  short8 bf[4][2];
#pragma unroll
  for (int t = 0; t < 4; t++)
#pragma unroll
    for (int s = 0; s < 2; s++)
#pragma unroll
      for (int j = 0; j < 8; j++)
        bf[t][s][j] = (short)f2bf(W[(s * 32 + q * 8 + j) * 64 + t * 16 + m]);

  float bias[4];
#pragma unroll
  for (int t = 0; t < 4; t++) bias[t] = b[t * 16 + m];

  float sc[2][8], sh[2][8];
#pragma unroll
  for (int s = 0; s < 2; s++)
#pragma unroll
    for (int j = 0; j < 8; j++) {
      sc[s][j] = scale_in[s * 32 + q * 8 + j];
      sh[s][j] = shift_in[s * 32 + q * 8 + j];
    }

  float psum[4] = {0.f, 0.f, 0.f, 0.f}, psq[4] = {0.f, 0.f, 0.f, 0.f};

  int tiles = E >> 4;
  int gw = ((int)blockIdx.x * (blockDim.x >> 6)) + (threadIdx.x >> 6);
  int nw = (int)gridDim.x * (blockDim.x >> 6);

  for (int tile = gw; tile < tiles; tile += nw) {
    long e0 = (long)tile * 16;
    const u16* rowp = h + (e0 + m) * 64;
    short8 a[2];
#pragma unroll
    for (int s = 0; s < 2; s++) {
      uint4 raw = *(const uint4*)(rowp + s * 32 + q * 8);
      unsigned rw[4] = {raw.x, raw.y, raw.z, raw.w};
#pragma unroll
      for (int p = 0; p < 4; p++) {
        float v0 = bf2f((u16)(rw[p] & 0xFFFFu));
        float v1 = bf2f((u16)(rw[p] >> 16));
        v0 = fmaf(v0, sc[s][2 * p], sh[s][2 * p]);
        v1 = fmaf(v1, sc[s][2 * p + 1], sh[s][2 * p + 1]);
        a[s][2 * p] = (short)f2bf(v0);
        a[s][2 * p + 1] = (short)f2bf(v1);
      }
    }
    floatx4 acc[4];
#pragma unroll
    for (int t = 0; t < 4; t++) acc[t] = (floatx4){0.f, 0.f, 0.f, 0.f};
#pragma unroll
    for (int t = 0; t < 4; t++)
      acc[t] = __builtin_amdgcn_mfma_f32_16x16x32_bf16(a[0], bf[t][0], acc[t], 0, 0, 0);
#pragma unroll
    for (int t = 0; t < 4; t++)
      acc[t] = __builtin_amdgcn_mfma_f32_16x16x32_bf16(a[1], bf[t][1], acc[t], 0, 0, 0);

#pragma unroll
    for (int t = 0; t < 4; t++) {
#pragma unroll
      for (int r = 0; r < 4; r++) {
        float v = acc[t][r] + bias[t];
        v = fmaxf(v, 0.f);
        u16 hb = f2bf(v);
        h[(e0 + q * 4 + r) * 64 + t * 16 + m] = hb;
        float hf = bf2f(hb);
        psum[t] += hf;
        psq[t] = fmaf(hf, hf, psq[t]);
      }
    }
  }

#pragma unroll
  for (int t = 0; t < 4; t++) {
    psum[t] += __shfl_xor(psum[t], 16, 64);
    psum[t] += __shfl_xor(psum[t], 32, 64);
    psq[t] += __shfl_xor(psq[t], 16, 64);
    psq[t] += __shfl_xor(psq[t], 32, 64);
  }
  __shared__ float ssum[64], ssq[64];
  if (threadIdx.x < 64) { ssum[threadIdx.x] = 0.f; ssq[threadIdx.x] = 0.f; }
  __syncthreads();
  if (q == 0) {
#pragma unroll
    for (int t = 0; t < 4; t++) {
      atomicAdd(&ssum[t * 16 + m], psum[t]);
      atomicAdd(&ssq[t * 16 + m], psq[t]);
    }
  }
  __syncthreads();
  if (threadIdx.x < 64) {
    atomicAdd(&gsum[threadIdx.x], ssum[threadIdx.x]);
    atomicAdd(&gsq[threadIdx.x], ssq[threadIdx.x]);
  }
}

// ---------------------------------------------------------------------------
// fallback path kernels (only if ws too small): -inf init, atomic scatter, fixup
__global__ void k_initout(float* __restrict__ outf, long n, float* __restrict__ stats,
                          u32* __restrict__ bucketTotal) {
  long i = (long)blockIdx.x * blockDim.x + threadIdx.x;
  long stride = (long)gridDim.x * blockDim.x;
  for (long j = i; j < n; j += stride) outf[j] = __uint_as_float(0xFF800000u);
  if (i < 1024) stats[i] = 0.f;
  if (i < NBMAX + 1) bucketTotal[i] = 0u;
}
__global__ void k_scatter(const int* __restrict__ ei, const u16* __restrict__ h,
                          const float* __restrict__ scale, const float* __restrict__ shift,
                          float* outf, int E) {
  int lane = threadIdx.x & 63;
  int gw = ((int)blockIdx.x * (blockDim.x >> 6)) + (threadIdx.x >> 6);
  int nw = (int)gridDim.x * (blockDim.x >> 6);
  float sc = scale[lane], sh = shift[lane];
  for (int e = gw; e < E; e += nw) {
    int d = ei[E + e];
    float v = fmaf(bf2f(h[(long)e * 64 + lane]), sc, sh);
    float* addr = outf + (long)d * 64 + lane;
    if (v >= 0.f)
      atomicMax((int*)addr, __float_as_int(v));
    else
      atomicMin((unsigned int*)addr, __float_as_uint(v));
  }
}
__global__ void k_out(float* __restrict__ outf, long n) {
  long i = (long)blockIdx.x * blockDim.x + threadIdx.x;
  long stride = (long)gridDim.x * blockDim.x;
  for (long j = i; j < n; j += stride) {
    float v = outf[j];
    unsigned u = __float_as_uint(v);
    if ((u & 0x7F800000u) == 0x7F800000u) v = 0.f;
    outf[j] = v;
  }
}

// ---------------------------------------------------------------------------
extern "C" void kernel_launch(void* const* d_in, const int* in_sizes, int n_in,
                              void* d_out, int out_size, void* d_ws, size_t ws_size,
                              hipStream_t stream) {
  const float* x = (const float*)d_in[0];
  const float* pos = (const float*)d_in[1];
  const int* ei = (const int*)d_in[2];
  const float* W1 = (const float*)d_in[3];
  const float* b1 = (const float*)d_in[4];
  const float* g1 = (const float*)d_in[5];
  const float* be1 = (const float*)d_in[6];
  const float* W2 = (const float*)d_in[7];
  const float* b2 = (const float*)d_in[8];
  const float* g2 = (const float*)d_in[9];
  const float* be2 = (const float*)d_in[10];
  const float* W3 = (const float*)d_in[11];
  const float* b3 = (const float*)d_in[12];
  const float* g3 = (const float*)d_in[13];
  const float* be3 = (const float*)d_in[14];

  int N = in_sizes[0] / 3;
  int E = in_sizes[2] / 2;
  int NB = (N + NPB - 1) / NPB;
  long n_out = (long)N * 64;

  char* wsb = (char*)d_ws;
  u16* h = (u16*)wsb;  // [E,64] bf16 activations
  size_t off = (size_t)E * 64 * 2;
  float* stats = (float*)(wsb + off);
  off += 1024 * 4;
  u32* bucketTotal = (u32*)(wsb + off);
  off += (NBMAX + 1) * 4;
  u32* baseArr = (u32*)(wsb + off);
  off += (NBMAX + 1) * 4;
  u32* cursor = (u32*)(wsb + off);
  off += NBMAX * 4;
  u32* sorted = (u32*)(wsb + off);
  off += (size_t)E * 4;
  size_t need = off;

  float* gsum1 = stats + 64, * gsq1 = stats + 128;
  float* gsum2 = stats + 192, * gsq2 = stats + 256;
  float* gsum3 = stats + 320, * gsq3 = stats + 384;
  float* sc1 = stats + 512, * sh1 = stats + 576;
  float* sc2 = stats + 640, * sh2 = stats + 704;
  float* sc3 = stats + 768, * sh3 = stats + 832;

  float* outf = (float*)d_out;
  float invE = 1.0f / (float)E;
  bool binned = (ws_size >= need) && (NB <= NBMAX);

  if (binned) {
    k_init<<<1, 1024, 0, stream>>>(stats, bucketTotal);
    k_norm_hist<<<256, 256, 0, stream>>>(ei, pos, E, NB, stats, bucketTotal);
    k_scan<<<1, 64, 0, stream>>>(bucketTotal, baseArr, cursor, NB);
    k_place<<<256, 256, 0, stream>>>(ei, E, NB, cursor, sorted);
    k_layer1<<<2048, 256, 0, stream>>>(ei, pos, x, W1, b1, h, stats, gsum1, gsq1, E);
    k_fin<<<1, 64, 0, stream>>>(gsum1, gsq1, g1, be1, sc1, sh1, invE);
    k_layer_mfma<<<1024, 256, 0, stream>>>(h, W2, b2, sc1, sh1, gsum2, gsq2, E);
    k_fin<<<1, 64, 0, stream>>>(gsum2, gsq2, g2, be2, sc2, sh2, invE);
    k_layer_mfma<<<1024, 256, 0, stream>>>(h, W3, b3, sc2, sh2, gsum3, gsq3, E);
    k_fin<<<1, 64, 0, stream>>>(gsum3, gsq3, g3, be3, sc3, sh3, invE);
    k_bucket_max<<<NB, 512, 0, stream>>>(sorted, baseArr, h, sc3, sh3, outf, N);
  } else {
    k_initout<<<4096, 256, 0, stream>>>(outf, n_out, stats, bucketTotal);
    k_norm_hist<<<256, 256, 0, stream>>>(ei, pos, E, NB <= NBMAX ? NB : 1, stats, bucketTotal);
    k_layer1<<<2048, 256, 0, stream>>>(ei, pos, x, W1, b1, h, stats, gsum1, gsq1, E);
    k_fin<<<1, 64, 0, stream>>>(gsum1, gsq1, g1, be1, sc1, sh1, invE);
    k_layer_mfma<<<1024, 256, 0, stream>>>(h, W2, b2, sc1, sh1, gsum2, gsq2, E);
    k_fin<<<1, 64, 0, stream>>>(gsum2, gsq2, g2, be2, sc2, sh2, invE);
    k_layer_mfma<<<1024, 256, 0, stream>>>(h, W3, b3, sc2, sh2, gsum3, gsq3, E);
    k_fin<<<1, 64, 0, stream>>>(gsum3, gsq3, g3, be3, sc3, sh3, invE);
    k_scatter<<<2048, 256, 0, stream>>>(ei, h, sc3, sh3, outf, E);
    k_out<<<2048, 256, 0, stream>>>(outf, n_out);
  }
}

// Round 3
// 512.827 us; speedup vs baseline: 2.1784x; 1.2248x over previous
//
#include <hip/hip_runtime.h>
#include <stdint.h>

typedef unsigned short u16;
typedef unsigned int u32;
typedef __attribute__((ext_vector_type(8))) short short8;
typedef __attribute__((ext_vector_type(4))) float floatx4;

#define BN_EPS 1e-5f
#define NPB 256    // nodes per bucket (power of 2; bucket = dst >> 8)
#define NBMAX 512

__device__ __forceinline__ float bf2f(u16 u) { return __uint_as_float(((unsigned)u) << 16); }
__device__ __forceinline__ u16 f2bf(float f) {
  unsigned u = __float_as_uint(f);
  u += 0x7FFFu + ((u >> 16) & 1u);   // round-to-nearest-even
  return (u16)(u >> 16);
}
// order-preserving float<->u32 key (key 0 == "empty"; relu outputs >= 0)
__device__ __forceinline__ u32 fkey(float f) {
  unsigned u = __float_as_uint(f);
  return (u >> 31) ? ~u : (u | 0x80000000u);
}
__device__ __forceinline__ float funkey(u32 k) {
  return (k & 0x80000000u) ? __uint_as_float(k ^ 0x80000000u) : __uint_as_float(~k);
}

// ---------------------------------------------------------------------------
// zero the small control block (stats + bucket totals)
__global__ void k_init(float* __restrict__ stats, u32* __restrict__ bucketTotal) {
  for (int i = threadIdx.x; i < 1024; i += blockDim.x) stats[i] = 0.f;
  for (int i = threadIdx.x; i < NBMAX + 1; i += blockDim.x) bucketTotal[i] = 0u;
}

// ---------------------------------------------------------------------------
// fused: global sum-of-squares of directions + per-bucket dst histogram
__global__ void k_norm_hist(const int* __restrict__ ei, const float* __restrict__ pos,
                            int E, int NB, float* __restrict__ stats,
                            u32* __restrict__ bucketTotal) {
  __shared__ u32 lh[NBMAX];
  __shared__ float red[16];
  for (int i = threadIdx.x; i < NB; i += blockDim.x) lh[i] = 0u;
  __syncthreads();
  int tid = blockIdx.x * blockDim.x + threadIdx.x;
  int stride = gridDim.x * blockDim.x;
  float acc = 0.f;
  for (int e = tid; e < E; e += stride) {
    int s = ei[e], d = ei[E + e];
    float d0 = pos[3 * s + 0] - pos[3 * d + 0];
    float d1 = pos[3 * s + 1] - pos[3 * d + 1];
    float d2 = pos[3 * s + 2] - pos[3 * d + 2];
    acc = fmaf(d0, d0, acc);
    acc = fmaf(d1, d1, acc);
    acc = fmaf(d2, d2, acc);
    atomicAdd(&lh[d >> 8], 1u);
  }
#pragma unroll
  for (int off = 32; off > 0; off >>= 1) acc += __shfl_down(acc, off, 64);
  if ((threadIdx.x & 63) == 0) red[threadIdx.x >> 6] = acc;
  __syncthreads();
  if (threadIdx.x == 0) {
    float s = 0.f;
    for (int w = 0; w < (int)(blockDim.x >> 6); w++) s += red[w];
    atomicAdd(&stats[0], s);
  }
  for (int i = threadIdx.x; i < NB; i += blockDim.x)
    if (lh[i]) atomicAdd(&bucketTotal[i], lh[i]);
}

// ---------------------------------------------------------------------------
// exclusive scan of bucket totals (tiny; single thread)
__global__ void k_scan(const u32* __restrict__ bucketTotal, u32* __restrict__ base,
                       u32* __restrict__ cursor, int NB) {
  if (threadIdx.x == 0 && blockIdx.x == 0) {
    u32 run = 0;
    for (int b = 0; b < NB; b++) {
      base[b] = run;
      cursor[b] = run;
      run += bucketTotal[b];
    }
    base[NB] = run;
  }
}

// ---------------------------------------------------------------------------
// bin edge ids by dst bucket: sorted[slot] = (e << 8) | (dst & 255)
__global__ void k_place(const int* __restrict__ ei, int E, int NB,
                        u32* __restrict__ cursor, u32* __restrict__ sorted) {
  __shared__ u32 lh[NBMAX];
  __shared__ u32 lbase[NBMAX];
  for (int i = threadIdx.x; i < NB; i += blockDim.x) lh[i] = 0u;
  __syncthreads();
  int tid = blockIdx.x * blockDim.x + threadIdx.x;
  int stride = gridDim.x * blockDim.x;
  for (int e = tid; e < E; e += stride) atomicAdd(&lh[ei[E + e] >> 8], 1u);
  __syncthreads();
  for (int i = threadIdx.x; i < NB; i += blockDim.x) {
    u32 c = lh[i];
    lbase[i] = c ? atomicAdd(&cursor[i], c) : 0u;
    lh[i] = 0u;
  }
  __syncthreads();
  for (int e = tid; e < E; e += stride) {
    int d = ei[E + e];
    int b = d >> 8;
    u32 slot = lbase[b] + atomicAdd(&lh[b], 1u);
    sorted[slot] = ((u32)e << 8) | (u32)(d & 255);
  }
}

// ---------------------------------------------------------------------------
// per-bucket scatter-max in LDS: gather h3 rows, apply BN3, atomicMax keys,
// then one coalesced write of the 256-node tile. Empty nodes -> 0.
__global__ __launch_bounds__(512) void k_bucket_max(
    const u32* __restrict__ sorted, const u32* __restrict__ base,
    const u16* __restrict__ h, const float* __restrict__ sc3,
    const float* __restrict__ sh3, float* __restrict__ outf, int N) {
  __shared__ u32 tile[NPB * 64];  // 64 KB of order-preserving keys
  for (int i = threadIdx.x; i < NPB * 64; i += blockDim.x) tile[i] = 0u;
  int b = blockIdx.x;
  u32 start = base[b];
  int cnt = (int)(base[b + 1] - start);
  int t = threadIdx.x;
  int es = t >> 3;       // edge slot 0..63
  int c0 = (t & 7) * 8;  // this thread's 8 channels
  float sc[8], sh[8];
#pragma unroll
  for (int j = 0; j < 8; j++) { sc[j] = sc3[c0 + j]; sh[j] = sh3[c0 + j]; }
  __syncthreads();

  for (int i0 = 0; i0 < cnt; i0 += 256) {  // 64 edges x 4-deep unroll
    u32 pk[4];
    uint4 raw[4];
    int ok[4];
#pragma unroll
    for (int u_ = 0; u_ < 4; u_++) {
      int sl = i0 + u_ * 64 + es;
      ok[u_] = sl < cnt;
      pk[u_] = ok[u_] ? sorted[start + sl] : 0u;
    }
#pragma unroll
    for (int u_ = 0; u_ < 4; u_++)
      if (ok[u_]) raw[u_] = *(const uint4*)(h + (long)(pk[u_] >> 8) * 64 + c0);
#pragma unroll
    for (int u_ = 0; u_ < 4; u_++) {
      if (!ok[u_]) continue;
      int ln = (int)(pk[u_] & 255u);
      unsigned w[4] = {raw[u_].x, raw[u_].y, raw[u_].z, raw[u_].w};
      u32 key[8];
#pragma unroll
      for (int p = 0; p < 4; p++) {
        float v0 = bf2f((u16)(w[p] & 0xFFFFu));
        float v1 = bf2f((u16)(w[p] >> 16));
        key[2 * p] = fkey(fmaf(v0, sc[2 * p], sh[2 * p]));
        key[2 * p + 1] = fkey(fmaf(v1, sc[2 * p + 1], sh[2 * p + 1]));
      }
      // per-edge-slot rotated channel order -> 2 lanes/bank (conflict-free)
#pragma unroll
      for (int jj = 0; jj < 8; jj++) {
        int j = (jj + es) & 7;
        atomicMax(&tile[ln * 64 + c0 + j], key[j]);
      }
    }
  }
  __syncthreads();
  int node0 = b * NPB;
  for (int l = t; l < NPB * 64; l += blockDim.x) {
    int node = node0 + (l >> 6);
    if (node < N) {
      u32 k = tile[l];
      outf[(long)node * 64 + (l & 63)] = (k == 0u) ? 0.f : funkey(k);
    }
  }
}

// ---------------------------------------------------------------------------
// layer 1, two-phase: phase A = 256 parallel gathers -> LDS; phase B = wave
// per edge from LDS (6 fma), bf16 store, fused stats. 256 edges per chunk.
__global__ __launch_bounds__(256) void k_layer1(
    const int* __restrict__ ei, const float* __restrict__ pos,
    const float* __restrict__ x, const float* __restrict__ W1,
    const float* __restrict__ b1, u16* __restrict__ h,
    const float* __restrict__ stats, float* __restrict__ gsum,
    float* __restrict__ gsq, int E) {
  __shared__ float in6[6][256];
  __shared__ float ssum[64], ssq[64];
  float invn = 1.0f / sqrtf(stats[0]);
  int t = threadIdx.x;
  int lane = t & 63;
  int wv = t >> 6;
  float w[6];
#pragma unroll
  for (int k = 0; k < 6; k++) w[k] = W1[k * 64 + lane];
  float bias = b1[lane];
  float psum = 0.f, psq = 0.f;

  int chunks = (E + 255) >> 8;
  for (int c = blockIdx.x; c < chunks; c += gridDim.x) {
    long e0 = (long)c << 8;
    int e = (int)e0 + t;
    float v[6] = {0.f, 0.f, 0.f, 0.f, 0.f, 0.f};
    if (e < E) {
      int s = ei[e], d = ei[E + e];
      float p0 = pos[3 * s + 0], p1 = pos[3 * s + 1], p2 = pos[3 * s + 2];
      float q0 = pos[3 * d + 0], q1 = pos[3 * d + 1], q2 = pos[3 * d + 2];
      v[0] = (p0 - q0) * invn;
      v[1] = (p1 - q1) * invn;
      v[2] = (p2 - q2) * invn;
      v[3] = x[3 * d + 0];
      v[4] = x[3 * d + 1];
      v[5] = x[3 * d + 2];
    }
    __syncthreads();  // previous chunk's phase-B reads done
#pragma unroll
    for (int k = 0; k < 6; k++) in6[k][t] = v[k];
    __syncthreads();
    int lim = E - (int)e0;
    if (lim > 256) lim = 256;
    int base = wv * 64;
#pragma unroll 4
    for (int i = 0; i < 64; i++) {
      int el = base + i;
      if (el >= lim) break;
      float acc = bias;
#pragma unroll
      for (int k = 0; k < 6; k++) acc = fmaf(in6[k][el], w[k], acc);
      acc = fmaxf(acc, 0.f);
      u16 hb = f2bf(acc);
      h[(e0 + el) * 64 + lane] = hb;
      float hf = bf2f(hb);
      psum += hf;
      psq = fmaf(hf, hf, psq);
    }
  }
  if (t < 64) { ssum[t] = 0.f; ssq[t] = 0.f; }
  __syncthreads();
  atomicAdd(&ssum[lane], psum);
  atomicAdd(&ssq[lane], psq);
  __syncthreads();
  if (t < 64) {
    atomicAdd(&gsum[t], ssum[t]);
    atomicAdd(&gsq[t], ssq[t]);
  }
}

// ---------------------------------------------------------------------------
// BN finalize (1 block, 64 thr)
__global__ void k_fin(const float* __restrict__ gsum, const float* __restrict__ gsq,
                      const float* __restrict__ g, const float* __restrict__ be,
                      float* __restrict__ scale, float* __restrict__ shift, float invE) {
  int c = threadIdx.x;
  float mu = gsum[c] * invE;
  float var = gsq[c] * invE - mu * mu;
  float s = g[c] * rsqrtf(var + BN_EPS);
  scale[c] = s;
  shift[c] = be[c] - mu * s;
}

// ---------------------------------------------------------------------------
// layers 2/3: h = relu( bn_in(h) @ W + b ), in place. Input-BN folded into
// W' = sc_in*W and bias' = b + sh_in^T W, so A-frags are RAW uint4 loads.
__global__ __launch_bounds__(256) void k_layer_mfma(
    u16* h, const float* __restrict__ W, const float* __restrict__ b,
    const float* __restrict__ scale_in, const float* __restrict__ shift_in,
    float* __restrict__ gsum, float* __restrict__ gsq, int E) {
  int lane = threadIdx.x & 63;
  int m = lane & 15;
  int q = lane >> 4;

  short8 bf[4][2];
  float bias[4];
#pragma unroll
  for (int t = 0; t < 4; t++) {
    int n = t * 16 + m;
    float bb = b[n];
    for (int k = 0; k < 64; k++) bb = fmaf(shift_in[k], W[k * 64 + n], bb);
    bias[t] = bb;
#pragma unroll
    for (int s = 0; s < 2; s++)
#pragma unroll
      for (int j = 0; j < 8; j++) {
        int k = s * 32 + q * 8 + j;
        bf[t][s][j] = (short)f2bf(W[k * 64 + n] * scale_in[k]);
      }
  }

  float psum[4] = {0.f, 0.f, 0.f, 0.f}, psq[4] = {0.f, 0.f, 0.f, 0.f};

  int tiles = E >> 4;
  int gw = ((int)blockIdx.x * (blockDim.x >> 6)) + (threadIdx.x >> 6);
  int nw = (int)gridDim.x * (blockDim.x >> 6);

  for (int tile = gw; tile < tiles; tile += nw) {
    long e0 = (long)tile * 16;
    const u16* rowp = h + (e0 + m) * 64 + q * 8;
    short8 a0 = *(const short8*)(rowp);
    short8 a1 = *(const short8*)(rowp + 32);
    floatx4 acc[4];
#pragma unroll
    for (int t = 0; t < 4; t++) acc[t] = (floatx4){0.f, 0.f, 0.f, 0.f};
#pragma unroll
    for (int t = 0; t < 4; t++)
      acc[t] = __builtin_amdgcn_mfma_f32_16x16x32_bf16(a0, bf[t][0], acc[t], 0, 0, 0);
#pragma unroll
    for (int t = 0; t < 4; t++)
      acc[t] = __builtin_amdgcn_mfma_f32_16x16x32_bf16(a1, bf[t][1], acc[t], 0, 0, 0);

#pragma unroll
    for (int t = 0; t < 4; t++) {
#pragma unroll
      for (int r = 0; r < 4; r++) {
        float v = acc[t][r] + bias[t];
        v = fmaxf(v, 0.f);
        u16 hb = f2bf(v);
        h[(e0 + q * 4 + r) * 64 + t * 16 + m] = hb;
        float hf = bf2f(hb);
        psum[t] += hf;
        psq[t] = fmaf(hf, hf, psq[t]);
      }
    }
  }

#pragma unroll
  for (int t = 0; t < 4; t++) {
    psum[t] += __shfl_xor(psum[t], 16, 64);
    psum[t] += __shfl_xor(psum[t], 32, 64);
    psq[t] += __shfl_xor(psq[t], 16, 64);
    psq[t] += __shfl_xor(psq[t], 32, 64);
  }
  __shared__ float ssum[64], ssq[64];
  if (threadIdx.x < 64) { ssum[threadIdx.x] = 0.f; ssq[threadIdx.x] = 0.f; }
  __syncthreads();
  if (q == 0) {
#pragma unroll
    for (int t = 0; t < 4; t++) {
      atomicAdd(&ssum[t * 16 + m], psum[t]);
      atomicAdd(&ssq[t * 16 + m], psq[t]);
    }
  }
  __syncthreads();
  if (threadIdx.x < 64) {
    atomicAdd(&gsum[threadIdx.x], ssum[threadIdx.x]);
    atomicAdd(&gsq[threadIdx.x], ssq[threadIdx.x]);
  }
}

// ---------------------------------------------------------------------------
// fallback path kernels (only if ws too small): -inf init, atomic scatter, fixup
__global__ void k_initout(float* __restrict__ outf, long n, float* __restrict__ stats,
                          u32* __restrict__ bucketTotal) {
  long i = (long)blockIdx.x * blockDim.x + threadIdx.x;
  long stride = (long)gridDim.x * blockDim.x;
  for (long j = i; j < n; j += stride) outf[j] = __uint_as_float(0xFF800000u);
  if (i < 1024) stats[i] = 0.f;
  if (i < NBMAX + 1) bucketTotal[i] = 0u;
}
__global__ void k_scatter(const int* __restrict__ ei, const u16* __restrict__ h,
                          const float* __restrict__ scale, const float* __restrict__ shift,
                          float* outf, int E) {
  int lane = threadIdx.x & 63;
  int gw = ((int)blockIdx.x * (blockDim.x >> 6)) + (threadIdx.x >> 6);
  int nw = (int)gridDim.x * (blockDim.x >> 6);
  float sc = scale[lane], sh = shift[lane];
  for (int e = gw; e < E; e += nw) {
    int d = ei[E + e];
    float v = fmaf(bf2f(h[(long)e * 64 + lane]), sc, sh);
    float* addr = outf + (long)d * 64 + lane;
    if (v >= 0.f)
      atomicMax((int*)addr, __float_as_int(v));
    else
      atomicMin((unsigned int*)addr, __float_as_uint(v));
  }
}
__global__ void k_out(float* __restrict__ outf, long n) {
  long i = (long)blockIdx.x * blockDim.x + threadIdx.x;
  long stride = (long)gridDim.x * blockDim.x;
  for (long j = i; j < n; j += stride) {
    float v = outf[j];
    unsigned u = __float_as_uint(v);
    if ((u & 0x7F800000u) == 0x7F800000u) v = 0.f;
    outf[j] = v;
  }
}

// ---------------------------------------------------------------------------
extern "C" void kernel_launch(void* const* d_in, const int* in_sizes, int n_in,
                              void* d_out, int out_size, void* d_ws, size_t ws_size,
                              hipStream_t stream) {
  const float* x = (const float*)d_in[0];
  const float* pos = (const float*)d_in[1];
  const int* ei = (const int*)d_in[2];
  const float* W1 = (const float*)d_in[3];
  const float* b1 = (const float*)d_in[4];
  const float* g1 = (const float*)d_in[5];
  const float* be1 = (const float*)d_in[6];
  const float* W2 = (const float*)d_in[7];
  const float* b2 = (const float*)d_in[8];
  const float* g2 = (const float*)d_in[9];
  const float* be2 = (const float*)d_in[10];
  const float* W3 = (const float*)d_in[11];
  const float* b3 = (const float*)d_in[12];
  const float* g3 = (const float*)d_in[13];
  const float* be3 = (const float*)d_in[14];

  int N = in_sizes[0] / 3;
  int E = in_sizes[2] / 2;
  int NB = (N + NPB - 1) / NPB;
  long n_out = (long)N * 64;

  char* wsb = (char*)d_ws;
  u16* h = (u16*)wsb;  // [E,64] bf16 activations
  size_t off = (size_t)E * 64 * 2;
  float* stats = (float*)(wsb + off);
  off += 1024 * 4;
  u32* bucketTotal = (u32*)(wsb + off);
  off += (NBMAX + 1) * 4;
  u32* baseArr = (u32*)(wsb + off);
  off += (NBMAX + 1) * 4;
  u32* cursor = (u32*)(wsb + off);
  off += NBMAX * 4;
  u32* sorted = (u32*)(wsb + off);
  off += (size_t)E * 4;
  size_t need = off;

  float* gsum1 = stats + 64, * gsq1 = stats + 128;
  float* gsum2 = stats + 192, * gsq2 = stats + 256;
  float* gsum3 = stats + 320, * gsq3 = stats + 384;
  float* sc1 = stats + 512, * sh1 = stats + 576;
  float* sc2 = stats + 640, * sh2 = stats + 704;
  float* sc3 = stats + 768, * sh3 = stats + 832;

  float* outf = (float*)d_out;
  float invE = 1.0f / (float)E;
  bool binned = (ws_size >= need) && (NB <= NBMAX);

  if (binned) {
    k_init<<<1, 1024, 0, stream>>>(stats, bucketTotal);
    k_norm_hist<<<256, 256, 0, stream>>>(ei, pos, E, NB, stats, bucketTotal);
    k_scan<<<1, 64, 0, stream>>>(bucketTotal, baseArr, cursor, NB);
    k_place<<<256, 256, 0, stream>>>(ei, E, NB, cursor, sorted);
    k_layer1<<<1024, 256, 0, stream>>>(ei, pos, x, W1, b1, h, stats, gsum1, gsq1, E);
    k_fin<<<1, 64, 0, stream>>>(gsum1, gsq1, g1, be1, sc1, sh1, invE);
    k_layer_mfma<<<1024, 256, 0, stream>>>(h, W2, b2, sc1, sh1, gsum2, gsq2, E);
    k_fin<<<1, 64, 0, stream>>>(gsum2, gsq2, g2, be2, sc2, sh2, invE);
    k_layer_mfma<<<1024, 256, 0, stream>>>(h, W3, b3, sc2, sh2, gsum3, gsq3, E);
    k_fin<<<1, 64, 0, stream>>>(gsum3, gsq3, g3, be3, sc3, sh3, invE);
    k_bucket_max<<<NB, 512, 0, stream>>>(sorted, baseArr, h, sc3, sh3, outf, N);
  } else {
    k_initout<<<4096, 256, 0, stream>>>(outf, n_out, stats, bucketTotal);
    k_norm_hist<<<256, 256, 0, stream>>>(ei, pos, E, NB <= NBMAX ? NB : 1, stats, bucketTotal);
    k_layer1<<<1024, 256, 0, stream>>>(ei, pos, x, W1, b1, h, stats, gsum1, gsq1, E);
    k_fin<<<1, 64, 0, stream>>>(gsum1, gsq1, g1, be1, sc1, sh1, invE);
    k_layer_mfma<<<1024, 256, 0, stream>>>(h, W2, b2, sc1, sh1, gsum2, gsq2, E);
    k_fin<<<1, 64, 0, stream>>>(gsum2, gsq2, g2, be2, sc2, sh2, invE);
    k_layer_mfma<<<1024, 256, 0, stream>>>(h, W3, b3, sc2, sh2, gsum3, gsq3, E);
    k_fin<<<1, 64, 0, stream>>>(gsum3, gsq3, g3, be3, sc3, sh3, invE);
    k_scatter<<<2048, 256, 0, stream>>>(ei, h, sc3, sh3, outf, E);
    k_out<<<2048, 256, 0, stream>>>(outf, n_out);
  }
}